// Round 4
// baseline (7917.426 us; speedup 1.0000x reference)
//
#include <hip/hip_runtime.h>
#include <hip/hip_bf16.h>

#define BATCH 8192
#define INPUT 64
#define HIDDEN 512
#define OUTPUT 64
#define STEPS 100

typedef __bf16 bf16x8 __attribute__((ext_vector_type(8)));
typedef float f32x16 __attribute__((ext_vector_type(16)));

__device__ __forceinline__ float sigf(float x) { return 1.0f / (1.0f + __expf(-x)); }
// tanh(x) = 1 - 2/(1+exp(2x)); saturates correctly at +/-inf
__device__ __forceinline__ float tanh_fast(float x) { return 1.0f - 2.0f / (1.0f + __expf(2.0f * x)); }

// ---------------- weight conversion (fp32 -> bf16), once per launch ----------------
__global__ void convert_weights(const float* __restrict__ Wih, const float* __restrict__ Whh,
                                const float* __restrict__ Wout,
                                __bf16* __restrict__ wih, __bf16* __restrict__ whh,
                                __bf16* __restrict__ wout) {
    const int nih = 4 * HIDDEN * INPUT;    // 131072
    const int nhh = 4 * HIDDEN * HIDDEN;   // 1048576
    const int nout = OUTPUT * HIDDEN;      // 32768
    for (int idx = blockIdx.x * 256 + threadIdx.x; idx < nhh; idx += gridDim.x * 256) {
        whh[idx] = (__bf16)Whh[idx];
        if (idx < nih)  wih[idx]  = (__bf16)Wih[idx];
        if (idx < nout) wout[idx] = (__bf16)Wout[idx];
    }
}

// ---------------- state init: h = h0 broadcast (bf16), c = c0 broadcast, inp = 0 ----------------
// Runs every launch (harness re-poisons d_ws to 0xAA before each timed replay).
__global__ void init_state(const float* __restrict__ h0, const float* __restrict__ c0,
                           __bf16* __restrict__ h, float* __restrict__ c, __bf16* __restrict__ inp) {
    int idx = blockIdx.x * 256 + threadIdx.x;
    if (idx < BATCH * HIDDEN) {
        int j = idx & (HIDDEN - 1);
        h[idx] = (__bf16)h0[j];
        c[idx] = c0[j];
    }
    if (idx < BATCH * INPUT) inp[idx] = (__bf16)0.0f;
}

// ---------------- fused gates GEMM + LSTM cell update ----------------
// gates = [inp | h_in] @ [W_ih | W_hh]^T + b_lstm   (M=8192, N=4*512, K=64+512)
// Block: 256 thr = 4 waves stacked on M. Block tile: 256 rows x 32 hidden cols x 4 gates.
// Each wave: 64 rows (2 row-frags) x 32 cols x 4 gates via mfma_f32_32x32x16_bf16.
//   -> 6 fragment loads per 8 MFMAs (each B fragment amortized over 2 A fragments;
//      cross-wave B redundancy left to L1/L2 this round — LDS staging is the next lever
//      if the profile shows vmcnt stalls).
// A frag: row = lane&31, k = (lane>>5)*8 + [0..7]  (16B contiguous)
// B frag: col = lane&31, k = (lane>>5)*8 + [0..7]  -> reads W[n][k] row-contiguous
// C/D:    col = lane&31, row = (v&3) + 8*(v>>2) + 4*(lane>>5)   [guide §3, m74/m101]
// Grid (32,16) = 512 blocks = exactly 2 blocks/CU at 256 CUs -> no tail wave.
// Gates never touch HBM: consumed in-register by the cell epilogue.
__global__ __launch_bounds__(256, 2) void lstm_step(
    const __bf16* __restrict__ inp, const __bf16* __restrict__ h_in,
    const __bf16* __restrict__ wih, const __bf16* __restrict__ whh,
    const float* __restrict__ b_lstm,
    float* __restrict__ c, __bf16* __restrict__ h_out) {

    const int lane = threadIdx.x & 63;
    const int wave = threadIdx.x >> 6;
    const int r = lane & 31;
    const int koff = (lane >> 5) * 8;

    const int mBase = blockIdx.x * 256 + wave * 64;   // wave owns rows [mBase, mBase+64)
    const int hBase = blockIdx.y * 32;

    f32x16 acc[4][2];
#pragma unroll
    for (int g = 0; g < 4; ++g)
#pragma unroll
        for (int m = 0; m < 2; ++m)
#pragma unroll
            for (int v = 0; v < 16; ++v) acc[g][m][v] = 0.0f;

    const int arow = mBase + r;
    const __bf16* aI = inp + arow * INPUT + koff;
    const __bf16* aH = h_in + arow * HIDDEN + koff;
    const int ncol = hBase + r;  // B-operand column (hidden index within gate)

    // K-part 1: input contribution, k in [0,64)
#pragma unroll
    for (int kk = 0; kk < INPUT / 16; ++kk) {
        bf16x8 a0 = *reinterpret_cast<const bf16x8*>(aI + kk * 16);
        bf16x8 a1 = *reinterpret_cast<const bf16x8*>(aI + 32 * INPUT + kk * 16);
#pragma unroll
        for (int g = 0; g < 4; ++g) {
            const __bf16* bp = wih + (g * HIDDEN + ncol) * INPUT + koff + kk * 16;
            bf16x8 b = *reinterpret_cast<const bf16x8*>(bp);
            acc[g][0] = __builtin_amdgcn_mfma_f32_32x32x16_bf16(a0, b, acc[g][0], 0, 0, 0);
            acc[g][1] = __builtin_amdgcn_mfma_f32_32x32x16_bf16(a1, b, acc[g][1], 0, 0, 0);
        }
    }
    // K-part 2: hidden contribution, k in [0,512)
#pragma unroll 2
    for (int kk = 0; kk < HIDDEN / 16; ++kk) {
        bf16x8 a0 = *reinterpret_cast<const bf16x8*>(aH + kk * 16);
        bf16x8 a1 = *reinterpret_cast<const bf16x8*>(aH + 32 * HIDDEN + kk * 16);
#pragma unroll
        for (int g = 0; g < 4; ++g) {
            const __bf16* bp = whh + (g * HIDDEN + ncol) * HIDDEN + koff + kk * 16;
            bf16x8 b = *reinterpret_cast<const bf16x8*>(bp);
            acc[g][0] = __builtin_amdgcn_mfma_f32_32x32x16_bf16(a0, b, acc[g][0], 0, 0, 0);
            acc[g][1] = __builtin_amdgcn_mfma_f32_32x32x16_bf16(a1, b, acc[g][1], 0, 0, 0);
        }
    }

    // epilogue: i,f,g,o share (row,col) mapping across the 4 accumulators
    const float bi = b_lstm[0 * HIDDEN + ncol];
    const float bf = b_lstm[1 * HIDDEN + ncol];
    const float bg = b_lstm[2 * HIDDEN + ncol];
    const float bo = b_lstm[3 * HIDDEN + ncol];
    const int rbase = 4 * (lane >> 5);
#pragma unroll
    for (int m = 0; m < 2; ++m) {
#pragma unroll
        for (int v = 0; v < 16; ++v) {
            int row = mBase + m * 32 + (v & 3) + 8 * (v >> 2) + rbase;
            float iv = sigf(acc[0][m][v] + bi);
            float fv = sigf(acc[1][m][v] + bf);
            float gv = tanh_fast(acc[2][m][v] + bg);
            float ov = sigf(acc[3][m][v] + bo);
            float cold = c[row * HIDDEN + ncol];
            float cnew = fv * cold + iv * gv;
            c[row * HIDDEN + ncol] = cnew;  // c stays fp32: no drift from storage rounding
            h_out[row * HIDDEN + ncol] = (__bf16)(ov * tanh_fast(cnew));
        }
    }
}

// ---------------- output GEMM: out = h @ W_out^T + b_out; also feeds back as next inp ----------------
// Block: 128 thr = 2 waves side-by-side on N. Tile: 32 rows x 64 cols. Grid: 256 blocks
// (spreads this tiny critical-path kernel across all 256 CUs).
__global__ __launch_bounds__(128, 2) void out_step(
    const __bf16* __restrict__ h, const __bf16* __restrict__ wout,
    const float* __restrict__ b_out, float* __restrict__ out,
    __bf16* __restrict__ inp_next, int t) {

    const int lane = threadIdx.x & 63;
    const int wave = threadIdx.x >> 6;
    const int r = lane & 31;
    const int koff = (lane >> 5) * 8;

    const int mBase = blockIdx.x * 32;
    const int nBase = wave * 32;

    f32x16 acc;
#pragma unroll
    for (int v = 0; v < 16; ++v) acc[v] = 0.0f;

    const __bf16* ap = h + (mBase + r) * HIDDEN + koff;
    const __bf16* bp = wout + (nBase + r) * HIDDEN + koff;
#pragma unroll 8
    for (int kk = 0; kk < HIDDEN / 16; ++kk) {
        bf16x8 a = *reinterpret_cast<const bf16x8*>(ap + kk * 16);
        bf16x8 b = *reinterpret_cast<const bf16x8*>(bp + kk * 16);
        acc = __builtin_amdgcn_mfma_f32_32x32x16_bf16(a, b, acc, 0, 0, 0);
    }

    const int col = nBase + r;
    const float bo = b_out[col];
    const int rbase = 4 * (lane >> 5);
#pragma unroll
    for (int v = 0; v < 16; ++v) {
        int row = mBase + (v & 3) + 8 * (v >> 2) + rbase;
        float val = acc[v] + bo;
        out[row * (STEPS * OUTPUT) + t * OUTPUT + col] = val;   // (B, steps, O) fp32
        inp_next[row * INPUT + col] = (__bf16)val;              // feedback for step t+1
    }
}

extern "C" void kernel_launch(void* const* d_in, const int* in_sizes, int n_in,
                              void* d_out, int out_size, void* d_ws, size_t ws_size,
                              hipStream_t stream) {
    // inputs: x(unused — reference zeroes the initial context), W_ih, W_hh, b_lstm,
    //         h0, c0, W_out, b_out, steps
    const float* W_ih   = (const float*)d_in[1];
    const float* W_hh   = (const float*)d_in[2];
    const float* b_lstm = (const float*)d_in[3];
    const float* h0     = (const float*)d_in[4];
    const float* c0     = (const float*)d_in[5];
    const float* W_out  = (const float*)d_in[6];
    const float* b_out  = (const float*)d_in[7];
    float* out = (float*)d_out;

    // workspace layout (~35.3 MB total)
    char* ws = (char*)d_ws;
    size_t off = 0;
    auto alloc = [&](size_t bytes) -> void* {
        void* p = ws + off;
        off += (bytes + 255) & ~(size_t)255;
        return p;
    };
    __bf16* wih  = (__bf16*)alloc((size_t)4 * HIDDEN * INPUT * 2);
    __bf16* whh  = (__bf16*)alloc((size_t)4 * HIDDEN * HIDDEN * 2);
    __bf16* wout = (__bf16*)alloc((size_t)OUTPUT * HIDDEN * 2);
    __bf16* hA   = (__bf16*)alloc((size_t)BATCH * HIDDEN * 2);
    __bf16* hB   = (__bf16*)alloc((size_t)BATCH * HIDDEN * 2);
    float*  c    = (float*)alloc((size_t)BATCH * HIDDEN * 4);
    __bf16* inp  = (__bf16*)alloc((size_t)BATCH * INPUT * 2);

    convert_weights<<<1024, 256, 0, stream>>>(W_ih, W_hh, W_out, wih, whh, wout);
    init_state<<<(BATCH * HIDDEN + 255) / 256, 256, 0, stream>>>(h0, c0, hA, c, inp);

    __bf16* hc = hA;
    __bf16* hn = hB;
    for (int t = 0; t < STEPS; ++t) {
        dim3 gA(BATCH / 256, HIDDEN / 32);
        lstm_step<<<gA, 256, 0, stream>>>(inp, hc, wih, whh, b_lstm, c, hn);
        out_step<<<BATCH / 32, 128, 0, stream>>>(hn, wout, b_out, out, inp, t);
        __bf16* tmp = hc; hc = hn; hn = tmp;  // double-buffer h (blocks read all cols)
    }
}

// Round 5
// 4394.559 us; speedup vs baseline: 1.8016x; 1.8016x over previous
//
#include <hip/hip_runtime.h>
#include <hip/hip_bf16.h>

#define BATCH 8192
#define INPUT 64
#define HIDDEN 512
#define OUTPUT 64
#define STEPS 100

typedef __bf16 bf16x8 __attribute__((ext_vector_type(8)));
typedef float f32x16 __attribute__((ext_vector_type(16)));

__device__ __forceinline__ float sigf(float x) { return 1.0f / (1.0f + __expf(-x)); }
// tanh(x) = 1 - 2/(1+exp(2x)); saturates correctly at +/-inf
__device__ __forceinline__ float tanh_fast(float x) { return 1.0f - 2.0f / (1.0f + __expf(2.0f * x)); }

// global->LDS async copy, 16B per lane. dst must be the wave-uniform base;
// HW scatters lane i to dst + i*16 (guide §5: wave-uniform base + lane*size).
__device__ __forceinline__ void load_lds16(const void* g, void* l) {
    __builtin_amdgcn_global_load_lds((const __attribute__((address_space(1))) void*)g,
                                     (__attribute__((address_space(3))) void*)l, 16, 0, 0);
}

// ---------------- weight pack (fp32 -> bf16), once per launch ----------------
// packedB layout: [16 yb][9 ck][128 row][64 e'] bf16, where
//   row = g*32 + cc  (g = gate, cc = col within 32-col block)  -> n = g*512 + yb*32 + cc
//   e'  = XOR-swizzled k-within-chunk: the CONTENT at e' is logical k = ck*64 + (e' ^ ((row&7)<<3)).
// global_load_lds writes LDS linearly, so baking the swizzle into the packed source
// (inverse-swz source + swz on read: rule #21, involution) gives bank-spread ds_reads.
__global__ void convert_weights(const float* __restrict__ Wih, const float* __restrict__ Whh,
                                const float* __restrict__ Wout,
                                __bf16* __restrict__ packedB, __bf16* __restrict__ wout) {
    const int NPACK = 16 * 9 * 128 * 64;  // 1179648
    for (int idx = blockIdx.x * 256 + threadIdx.x; idx < NPACK; idx += gridDim.x * 256) {
        int e_p = idx & 63;
        int row = (idx >> 6) & 127;
        int ck  = (idx >> 13) % 9;
        int yb  = (idx >> 13) / 9;
        int e = e_p ^ ((row & 7) << 3);       // undo the read-side XOR
        int k = ck * 64 + e;                  // logical k in [0,576)
        int n = ((row >> 5) << 9) + (yb << 5) + (row & 31);  // g*512 + yb*32 + cc
        float v = (k < 64) ? Wih[n * 64 + k] : Whh[n * 512 + (k - 64)];
        packedB[idx] = (__bf16)v;
    }
    for (int idx = blockIdx.x * 256 + threadIdx.x; idx < OUTPUT * HIDDEN; idx += gridDim.x * 256)
        wout[idx] = (__bf16)Wout[idx];
}

// ---------------- state init ----------------
__global__ void init_state(const float* __restrict__ h0, const float* __restrict__ c0,
                           __bf16* __restrict__ h, float* __restrict__ c, __bf16* __restrict__ inp) {
    int idx = blockIdx.x * 256 + threadIdx.x;
    if (idx < BATCH * HIDDEN) {
        int j = idx & (HIDDEN - 1);
        h[idx] = (__bf16)h0[j];
        c[idx] = c0[j];
    }
    if (idx < BATCH * INPUT) inp[idx] = (__bf16)0.0f;
}

// ---------------- fused gates GEMM + LSTM cell update ----------------
// gates = [inp | h_in] @ [W_ih | W_hh]^T + b_lstm  (M=8192, N=4*512, K=576 = 9 chunks of 64)
// Block: 4 waves on M. Tile 256 rows x 32 cols x 4 gates. B-tile staged in LDS
// (double-buffered 2x16KB) via global_load_lds from the pre-swizzled packed buffer;
// A (inp/h rows) direct global (per-wave-unique, L1-cached: 16KB/chunk/block).
// Per chunk per wave: 8 A-glb + 16 B-ds_read_b128 feed 32 MFMAs (2 rowfrag x 4 gate x 4 k).
// XCD swizzle: XCD x owns row-blocks [4x,4x+4) x all 16 col-blocks -> per-XCD L2 set:
// h-slab 1MB + c-slab 2MB + weights 2.25MB (fits 4MB-ish; was 8MB+ before).
__global__ __launch_bounds__(256, 2) void lstm_step(
    const __bf16* __restrict__ inp, const __bf16* __restrict__ h_in,
    const __bf16* __restrict__ packedB, const float* __restrict__ b_lstm,
    float* __restrict__ c, __bf16* __restrict__ h_out) {

    __shared__ __bf16 bsm[2][128][64];  // 32 KB

    const int lane = threadIdx.x & 63;
    const int wave = threadIdx.x >> 6;
    const int r = lane & 31;
    const int koff = (lane >> 5) * 8;

    const int bid = blockIdx.x;          // 512 blocks, 8 | 512 -> bijective xcd swizzle
    const int j = bid >> 3;
    const int rb = ((bid & 7) << 2) | (j & 3);   // row-block 0..31
    const int cb = j >> 2;                        // col-block 0..15

    const int mBase = rb * 256 + wave * 64;
    const int ncol = cb * 32 + r;
    const int arow = mBase + r;

    f32x16 acc[4][2];
#pragma unroll
    for (int g = 0; g < 4; ++g)
#pragma unroll
        for (int m = 0; m < 2; ++m)
#pragma unroll
            for (int v = 0; v < 16; ++v) acc[g][m][v] = 0.0f;

    const char* pB = (const char*)packedB;
    // stage chunk ck into bsm[buf]: 16KB, 4 waves x 4 instrs x 1KB, fully coalesced
    auto stage = [&](int ck, int buf) {
        const char* src = pB + (((size_t)(cb * 9 + ck)) << 14) + ((size_t)(wave * 4) << 10) + lane * 16;
        char* dst = (char*)&bsm[buf][0][0] + ((size_t)(wave * 4) << 10);
#pragma unroll
        for (int i = 0; i < 4; ++i)
            load_lds16(src + i * 1024, dst + i * 1024);
    };

    stage(0, 0);
    __syncthreads();   // drains vmcnt(0): chunk 0 resident

    int buf = 0;
    for (int ck = 0; ck < 9; ++ck) {
        if (ck < 8) stage(ck + 1, buf ^ 1);   // prefetch overlaps this chunk's MFMAs

        const __bf16* ap; int astr;
        if (ck == 0) { ap = inp + arow * INPUT;                    astr = 32 * INPUT; }
        else         { ap = h_in + arow * HIDDEN + (ck - 1) * 64;  astr = 32 * HIDDEN; }

        const __bf16* bb = &bsm[buf][0][0];
#pragma unroll
        for (int kk = 0; kk < 4; ++kk) {
            bf16x8 a0 = *reinterpret_cast<const bf16x8*>(ap + kk * 16 + koff);
            bf16x8 a1 = *reinterpret_cast<const bf16x8*>(ap + astr + kk * 16 + koff);
            const int eo = (kk * 16 + koff) ^ ((r & 7) << 3);   // read-side XOR (row&7 == r&7)
#pragma unroll
            for (int g = 0; g < 4; ++g) {
                bf16x8 b = *reinterpret_cast<const bf16x8*>(bb + (g * 32 + r) * 64 + eo);
                acc[g][0] = __builtin_amdgcn_mfma_f32_32x32x16_bf16(a0, b, acc[g][0], 0, 0, 0);
                acc[g][1] = __builtin_amdgcn_mfma_f32_32x32x16_bf16(a1, b, acc[g][1], 0, 0, 0);
            }
        }
        __syncthreads();  // next chunk staged AND all reads of buf done before overwrite
        buf ^= 1;
    }

    // epilogue: i,f,g,o meet per (row,col); C/D map col=lane&31, row=(v&3)+8*(v>>2)+4*(lane>>5)
    const float bi = b_lstm[0 * HIDDEN + ncol];
    const float bf = b_lstm[1 * HIDDEN + ncol];
    const float bg = b_lstm[2 * HIDDEN + ncol];
    const float bo = b_lstm[3 * HIDDEN + ncol];
    const int rbase = 4 * (lane >> 5);
#pragma unroll
    for (int m = 0; m < 2; ++m) {
#pragma unroll
        for (int v = 0; v < 16; ++v) {
            int row = mBase + m * 32 + (v & 3) + 8 * (v >> 2) + rbase;
            float iv = sigf(acc[0][m][v] + bi);
            float fv = sigf(acc[1][m][v] + bf);
            float gv = tanh_fast(acc[2][m][v] + bg);
            float ov = sigf(acc[3][m][v] + bo);
            float cold = c[row * HIDDEN + ncol];
            float cnew = fv * cold + iv * gv;
            c[row * HIDDEN + ncol] = cnew;  // fp32 cell state: no storage drift
            h_out[row * HIDDEN + ncol] = (__bf16)(ov * tanh_fast(cnew));
        }
    }
}

// ---------------- output GEMM: out = h @ W_out^T + b_out; feeds back as next inp ----------------
// 256 blocks x 2 waves; rows remapped so XCD x reads h rows [1024x,1024x+1024) — the slab
// the same XCD's lstm_step just wrote.
__global__ __launch_bounds__(128, 2) void out_step(
    const __bf16* __restrict__ h, const __bf16* __restrict__ wout,
    const float* __restrict__ b_out, float* __restrict__ out,
    __bf16* __restrict__ inp_next, int t) {

    const int lane = threadIdx.x & 63;
    const int wave = threadIdx.x >> 6;
    const int r = lane & 31;
    const int koff = (lane >> 5) * 8;

    const int bid = blockIdx.x;
    const int mBase = ((bid & 7) << 10) + ((bid >> 3) << 5);  // xcd*1024 + j*32
    const int nBase = wave * 32;

    f32x16 acc;
#pragma unroll
    for (int v = 0; v < 16; ++v) acc[v] = 0.0f;

    const __bf16* ap = h + (mBase + r) * HIDDEN + koff;
    const __bf16* bp = wout + (nBase + r) * HIDDEN + koff;
#pragma unroll 8
    for (int kk = 0; kk < HIDDEN / 16; ++kk) {
        bf16x8 a = *reinterpret_cast<const bf16x8*>(ap + kk * 16);
        bf16x8 b = *reinterpret_cast<const bf16x8*>(bp + kk * 16);
        acc = __builtin_amdgcn_mfma_f32_32x32x16_bf16(a, b, acc, 0, 0, 0);
    }

    const int col = nBase + r;
    const float bo = b_out[col];
    const int rbase = 4 * (lane >> 5);
#pragma unroll
    for (int v = 0; v < 16; ++v) {
        int row = mBase + (v & 3) + 8 * (v >> 2) + rbase;
        float val = acc[v] + bo;
        out[row * (STEPS * OUTPUT) + t * OUTPUT + col] = val;   // (B, steps, O) fp32
        inp_next[row * INPUT + col] = (__bf16)val;              // feedback for step t+1
    }
}

extern "C" void kernel_launch(void* const* d_in, const int* in_sizes, int n_in,
                              void* d_out, int out_size, void* d_ws, size_t ws_size,
                              hipStream_t stream) {
    // inputs: x(unused — reference zeroes the initial context), W_ih, W_hh, b_lstm,
    //         h0, c0, W_out, b_out, steps
    const float* W_ih   = (const float*)d_in[1];
    const float* W_hh   = (const float*)d_in[2];
    const float* b_lstm = (const float*)d_in[3];
    const float* h0     = (const float*)d_in[4];
    const float* c0     = (const float*)d_in[5];
    const float* W_out  = (const float*)d_in[6];
    const float* b_out  = (const float*)d_in[7];
    float* out = (float*)d_out;

    char* ws = (char*)d_ws;
    size_t off = 0;
    auto alloc = [&](size_t bytes) -> void* {
        void* p = ws + off;
        off += (bytes + 255) & ~(size_t)255;
        return p;
    };
    __bf16* packedB = (__bf16*)alloc((size_t)16 * 9 * 128 * 64 * 2);  // 2.25 MB
    __bf16* wout    = (__bf16*)alloc((size_t)OUTPUT * HIDDEN * 2);
    __bf16* hA      = (__bf16*)alloc((size_t)BATCH * HIDDEN * 2);
    __bf16* hB      = (__bf16*)alloc((size_t)BATCH * HIDDEN * 2);
    float*  c       = (float*)alloc((size_t)BATCH * HIDDEN * 4);
    __bf16* inp     = (__bf16*)alloc((size_t)BATCH * INPUT * 2);

    convert_weights<<<2048, 256, 0, stream>>>(W_ih, W_hh, W_out, packedB, wout);
    init_state<<<(BATCH * HIDDEN + 255) / 256, 256, 0, stream>>>(h0, c0, hA, c, inp);

    __bf16* hc = hA;
    __bf16* hn = hB;
    for (int t = 0; t < STEPS; ++t) {
        lstm_step<<<512, 256, 0, stream>>>(inp, hc, packedB, b_lstm, c, hn);
        out_step<<<BATCH / 32, 128, 0, stream>>>(hn, wout, b_out, out, inp, t);
        __bf16* tmp = hc; hc = hn; hn = tmp;  // double-buffer h (blocks read all cols)
    }
}